// Round 5
// baseline (33.304 us; speedup 1.0000x reference)
//
#include <hip/hip_runtime.h>

#define BB 32
#define TT 32
#define GT_PER 8
#define PER 32
#define NN 1024
#define DD 256
#define NFRAMES (BB * TT)   // 1024

__device__ __forceinline__ float dot4(float4 a, float4 b) {
    return a.x * b.x + a.y * b.y + a.z * b.z + a.w * b.w;
}

// One block per (scene, frame); the LAST block to finish reduces everything.
// Ticket counter: atomicInc with val=NFRAMES-1 wraps any start value >=1023
// (incl. the 0xAAAAAAAA poison) to 0 on the first arriver, so old==1022
// identifies the 1024th arriver and the counter self-restores to 1023.
__global__ __launch_bounds__(256, 4) void fused_kernel(
    const float* __restrict__ x, const float* __restrict__ conf,
    const int* __restrict__ ids, const float* __restrict__ scores,
    const int* __restrict__ tarr, const int* __restrict__ mi,
    float* __restrict__ frame_loss, float* __restrict__ frame_valid,
    unsigned int* __restrict__ counter, float* __restrict__ out)
{
    __shared__ float sgt[GT_PER * DD];      // 8 KiB: gt rows [8][256] linear
    __shared__ float sdot[PER * 9];         // raw dots, stride 9 (conflict-free)
    __shared__ float snorm[PER];
    __shared__ int   sids[PER], smi[PER], st[PER];
    __shared__ float sconf[PER], sscore[PER];
    __shared__ float sl[BB];                // scene partials (last-block epilogue)
    __shared__ int   is_last;

    const int tid = threadIdx.x;
    const int b = blockIdx.x / TT;
    const int f = blockIdx.x % TT;
    const long n0 = (long)b * NN + (long)f * PER;
    const float4* xg4 = (const float4*)(x + n0 * DD);   // 32 rows x 64 float4

    const int G = tid >> 4;        // 0..15
    const int l = tid & 15;        // lane in group
    const int r0 = 2 * G, r1 = r0 + 1;

    // ---- each group loads its 2 rows into registers (sole global read of x) ----
    float4 a0[4], a1[4];
    #pragma unroll
    for (int j = 0; j < 4; ++j) {
        a0[j] = xg4[r0 * 64 + l + 16 * j];
        a1[j] = xg4[r1 * 64 + l + 16 * j];
    }
    // groups 0..3 own rows 0..7 (the GT rows): publish them to LDS from registers
    if (G < 4) {
        #pragma unroll
        for (int j = 0; j < 4; ++j) {
            *(float4*)&sgt[(r0 * 64 + l + 16 * j) * 4] = a0[j];
            *(float4*)&sgt[(r1 * 64 + l + 16 * j) * 4] = a1[j];
        }
    }
    if (tid < PER) {
        sids[tid]   = ids[n0 + tid];
        smi[tid]    = mi[n0 + tid];
        st[tid]     = tarr[n0 + tid];
        sconf[tid]  = conf[n0 + tid];
        sscore[tid] = scores[n0 + tid];
    }
    __syncthreads();

    // ---- dots of own 2 rows vs 8 gt rows + own norms ----
    {
        float nrm0 = 0.f, nrm1 = 0.f;
        #pragma unroll
        for (int j = 0; j < 4; ++j) {
            nrm0 += dot4(a0[j], a0[j]);
            nrm1 += dot4(a1[j], a1[j]);
        }
        float d0[GT_PER], d1[GT_PER];
        #pragma unroll
        for (int c = 0; c < GT_PER; ++c) {
            float s0 = 0.f, s1 = 0.f;
            #pragma unroll
            for (int j = 0; j < 4; ++j) {
                float4 bv = *(const float4*)&sgt[(c * 64 + l + 16 * j) * 4];
                s0 += dot4(a0[j], bv);
                s1 += dot4(a1[j], bv);
            }
            d0[c] = s0; d1[c] = s1;
        }
        // 16-lane butterfly reduce (masks 1,2,4,8 stay within the group)
        #pragma unroll
        for (int m = 1; m < 16; m <<= 1) {
            nrm0 += __shfl_xor(nrm0, m);
            nrm1 += __shfl_xor(nrm1, m);
            #pragma unroll
            for (int c = 0; c < GT_PER; ++c) {
                d0[c] += __shfl_xor(d0[c], m);
                d1[c] += __shfl_xor(d1[c], m);
            }
        }
        if (l == 0) {
            snorm[r0] = nrm0;
            snorm[r1] = nrm1;
            #pragma unroll
            for (int c = 0; c < GT_PER; ++c) {
                sdot[r0 * 9 + c] = d0[c];
                sdot[r1 * 9 + c] = d1[c];
            }
        }
    }
    __syncthreads();

    // ---- per-row CE + MSE, frame reduction (wave 0), then ticket ----
    if (tid < 64) {
        int r = tid;
        float contrib = 0.f;
        int packed = 0;   // valid | det<<8 | gt<<16
        if (r < PER) {
            bool validr = sids[r] >= 0;
            bool detr = validr && (smi[r] != 0);
            bool gtr  = validr && (smi[r] == 0);
            packed = (validr ? 1 : 0) | ((detr ? 1 : 0) << 8) | ((gtr ? 1 : 0) << 16);
            if (detr) {
                float sinr = rsqrtf(snorm[r]);
                float m = -1e30f;
                float tgt = 0.f;
                float simv[GT_PER];
                int cvmask = 0;
                #pragma unroll
                for (int c = 0; c < GT_PER; ++c) {
                    bool cv = (sids[c] >= 0) && (smi[c] == 0) && (st[c] == st[r]);
                    float s = 10.f * sdot[r * 9 + c] * sinr * rsqrtf(snorm[c]);
                    simv[c] = s;
                    if (cv) {
                        cvmask |= (1 << c);
                        m = fmaxf(m, s);
                        if (sids[c] == sids[r]) tgt += s;
                    }
                }
                float se = 0.f;
                #pragma unroll
                for (int c = 0; c < GT_PER; ++c) {
                    if (cvmask & (1 << c)) se += expf(simv[c] - m);
                }
                float lse = m + logf(se);
                float ce = lse - tgt;
                float df = sconf[r] - sscore[r];
                contrib = ce + df * df;
            }
        }
        #pragma unroll
        for (int mask = 1; mask < 64; mask <<= 1) {
            contrib += __shfl_xor(contrib, mask);
            packed  += __shfl_xor(packed, mask);
        }
        if (tid == 0) {
            int vcnt = packed & 0xff;
            int dcnt = (packed >> 8) & 0xff;
            int gcnt = (packed >> 16) & 0xff;
            bool vf = (vcnt > 0) && (dcnt > 0) && (gcnt > 0);
            float denom = fmaxf((float)dcnt, 1.f);
            frame_loss[blockIdx.x]  = vf ? (contrib / denom) : 0.f;
            frame_valid[blockIdx.x] = vf ? 1.f : 0.f;
            __threadfence();   // release our slot device-wide
            unsigned int old = atomicInc(counter, NFRAMES - 1);
            is_last = (old == NFRAMES - 2) ? 1 : 0;
        }
    }
    __syncthreads();

    // ---- last arriving block reduces all frames ----
    if (is_last) {
        __threadfence();   // acquire side
        const int s  = tid >> 3;    // scene 0..31
        const int l8 = tid & 7;     // 8 lanes per scene
        float fl = 0.f, fv = 0.f;
        #pragma unroll
        for (int j = 0; j < 4; ++j) {
            int fr = l8 + 8 * j;
            fl += __hip_atomic_load(&frame_loss[s * TT + fr],
                                    __ATOMIC_RELAXED, __HIP_MEMORY_SCOPE_AGENT);
            fv += __hip_atomic_load(&frame_valid[s * TT + fr],
                                    __ATOMIC_RELAXED, __HIP_MEMORY_SCOPE_AGENT);
        }
        #pragma unroll
        for (int m = 1; m < 8; m <<= 1) {
            fl += __shfl_xor(fl, m);
            fv += __shfl_xor(fv, m);
        }
        if (l8 == 0) sl[s] = fl / fmaxf(fv, 1.f);
        __syncthreads();
        if (tid < 64) {
            float v = (tid < BB) ? sl[tid] : 0.f;
            #pragma unroll
            for (int m = 1; m < 64; m <<= 1) v += __shfl_xor(v, m);
            if (tid == 0) out[0] = v / (float)BB;
        }
    }
}

extern "C" void kernel_launch(void* const* d_in, const int* in_sizes, int n_in,
                              void* d_out, int out_size, void* d_ws, size_t ws_size,
                              hipStream_t stream) {
    const float* x      = (const float*)d_in[0];
    const float* conf   = (const float*)d_in[1];
    const int*   ids    = (const int*)d_in[2];
    const float* scores = (const float*)d_in[3];
    const int*   tarr   = (const int*)d_in[4];
    const int*   mi     = (const int*)d_in[5];
    float* out = (float*)d_out;

    float* frame_loss  = (float*)d_ws;                    // [1024]
    float* frame_valid = frame_loss + NFRAMES;            // [1024]
    unsigned int* counter = (unsigned int*)(frame_valid + NFRAMES);

    fused_kernel<<<dim3(NFRAMES), 256, 0, stream>>>(
        x, conf, ids, scores, tarr, mi, frame_loss, frame_valid, counter, out);
}

// Round 6
// 24.320 us; speedup vs baseline: 1.3694x; 1.3694x over previous
//
#include <hip/hip_runtime.h>

#define BB 32
#define TT 32
#define GT_PER 8
#define PER 32
#define NN 1024
#define DD 256
#define NFRAMES (BB * TT)   // 1024

__device__ __forceinline__ float dot4(float4 a, float4 b) {
    return a.x * b.x + a.y * b.y + a.z * b.z + a.w * b.w;
}

// One block per (scene, frame); the LAST block to finish reduces everything.
// Cross-XCD handoff uses agent-scope (sc1) atomic stores committed at the
// Infinity-Cache coherence point + s_waitcnt vmcnt(0) before the ticket RMW —
// no __threadfence (which lowers to buffer_wbl2 on gfx950 and cost ~20us).
// Ticket counter: atomicInc with val=NFRAMES-1 wraps any start value >=1023
// (incl. the 0xAAAAAAAA poison) to 0 on the first arriver, so old==1022
// identifies the 1024th arriver and the counter self-restores to 1023.
__global__ __launch_bounds__(256, 4) void fused_kernel(
    const float* __restrict__ x, const float* __restrict__ conf,
    const int* __restrict__ ids, const float* __restrict__ scores,
    const int* __restrict__ tarr, const int* __restrict__ mi,
    float* __restrict__ frame_loss, float* __restrict__ frame_valid,
    unsigned int* __restrict__ counter, float* __restrict__ out)
{
    __shared__ float sgt[GT_PER * DD];      // 8 KiB: gt rows [8][256] linear
    __shared__ float sdot[PER * 9];         // raw dots, stride 9 (conflict-free)
    __shared__ float snorm[PER];
    __shared__ int   sids[PER], smi[PER], st[PER];
    __shared__ float sconf[PER], sscore[PER];
    __shared__ float sl[BB];                // scene partials (last-block epilogue)
    __shared__ int   is_last;

    const int tid = threadIdx.x;
    const int b = blockIdx.x / TT;
    const int f = blockIdx.x % TT;
    const long n0 = (long)b * NN + (long)f * PER;
    const float4* xg4 = (const float4*)(x + n0 * DD);   // 32 rows x 64 float4

    const int G = tid >> 4;        // 0..15
    const int l = tid & 15;        // lane in group
    const int r0 = 2 * G, r1 = r0 + 1;

    // ---- each group loads its 2 rows into registers (sole global read of x) ----
    float4 a0[4], a1[4];
    #pragma unroll
    for (int j = 0; j < 4; ++j) {
        a0[j] = xg4[r0 * 64 + l + 16 * j];
        a1[j] = xg4[r1 * 64 + l + 16 * j];
    }
    // groups 0..3 own rows 0..7 (the GT rows): publish them to LDS from registers
    if (G < 4) {
        #pragma unroll
        for (int j = 0; j < 4; ++j) {
            *(float4*)&sgt[(r0 * 64 + l + 16 * j) * 4] = a0[j];
            *(float4*)&sgt[(r1 * 64 + l + 16 * j) * 4] = a1[j];
        }
    }
    if (tid < PER) {
        sids[tid]   = ids[n0 + tid];
        smi[tid]    = mi[n0 + tid];
        st[tid]     = tarr[n0 + tid];
        sconf[tid]  = conf[n0 + tid];
        sscore[tid] = scores[n0 + tid];
    }
    __syncthreads();

    // ---- dots of own 2 rows vs 8 gt rows + own norms ----
    {
        float nrm0 = 0.f, nrm1 = 0.f;
        #pragma unroll
        for (int j = 0; j < 4; ++j) {
            nrm0 += dot4(a0[j], a0[j]);
            nrm1 += dot4(a1[j], a1[j]);
        }
        float d0[GT_PER], d1[GT_PER];
        #pragma unroll
        for (int c = 0; c < GT_PER; ++c) {
            float s0 = 0.f, s1 = 0.f;
            #pragma unroll
            for (int j = 0; j < 4; ++j) {
                float4 bv = *(const float4*)&sgt[(c * 64 + l + 16 * j) * 4];
                s0 += dot4(a0[j], bv);
                s1 += dot4(a1[j], bv);
            }
            d0[c] = s0; d1[c] = s1;
        }
        // 16-lane butterfly reduce (masks 1,2,4,8 stay within the group)
        #pragma unroll
        for (int m = 1; m < 16; m <<= 1) {
            nrm0 += __shfl_xor(nrm0, m);
            nrm1 += __shfl_xor(nrm1, m);
            #pragma unroll
            for (int c = 0; c < GT_PER; ++c) {
                d0[c] += __shfl_xor(d0[c], m);
                d1[c] += __shfl_xor(d1[c], m);
            }
        }
        if (l == 0) {
            snorm[r0] = nrm0;
            snorm[r1] = nrm1;
            #pragma unroll
            for (int c = 0; c < GT_PER; ++c) {
                sdot[r0 * 9 + c] = d0[c];
                sdot[r1 * 9 + c] = d1[c];
            }
        }
    }
    __syncthreads();

    // ---- per-row CE + MSE, frame reduction (wave 0), then ticket ----
    if (tid < 64) {
        int r = tid;
        float contrib = 0.f;
        int packed = 0;   // valid | det<<8 | gt<<16
        if (r < PER) {
            bool validr = sids[r] >= 0;
            bool detr = validr && (smi[r] != 0);
            bool gtr  = validr && (smi[r] == 0);
            packed = (validr ? 1 : 0) | ((detr ? 1 : 0) << 8) | ((gtr ? 1 : 0) << 16);
            if (detr) {
                float sinr = rsqrtf(snorm[r]);
                float m = -1e30f;
                float tgt = 0.f;
                float simv[GT_PER];
                int cvmask = 0;
                #pragma unroll
                for (int c = 0; c < GT_PER; ++c) {
                    bool cv = (sids[c] >= 0) && (smi[c] == 0) && (st[c] == st[r]);
                    float s = 10.f * sdot[r * 9 + c] * sinr * rsqrtf(snorm[c]);
                    simv[c] = s;
                    if (cv) {
                        cvmask |= (1 << c);
                        m = fmaxf(m, s);
                        if (sids[c] == sids[r]) tgt += s;
                    }
                }
                float se = 0.f;
                #pragma unroll
                for (int c = 0; c < GT_PER; ++c) {
                    if (cvmask & (1 << c)) se += expf(simv[c] - m);
                }
                float lse = m + logf(se);
                float ce = lse - tgt;
                float df = sconf[r] - sscore[r];
                contrib = ce + df * df;
            }
        }
        #pragma unroll
        for (int mask = 1; mask < 64; mask <<= 1) {
            contrib += __shfl_xor(contrib, mask);
            packed  += __shfl_xor(packed, mask);
        }
        if (tid == 0) {
            int vcnt = packed & 0xff;
            int dcnt = (packed >> 8) & 0xff;
            int gcnt = (packed >> 16) & 0xff;
            bool vf = (vcnt > 0) && (dcnt > 0) && (gcnt > 0);
            float denom = fmaxf((float)dcnt, 1.f);
            // agent-scope write-through stores: visible at IF$ without L2 flush
            __hip_atomic_store(&frame_loss[blockIdx.x], vf ? (contrib / denom) : 0.f,
                               __ATOMIC_RELAXED, __HIP_MEMORY_SCOPE_AGENT);
            __hip_atomic_store(&frame_valid[blockIdx.x], vf ? 1.f : 0.f,
                               __ATOMIC_RELAXED, __HIP_MEMORY_SCOPE_AGENT);
            // commit slot stores at the coherence point before the ticket RMW
            asm volatile("s_waitcnt vmcnt(0)" ::: "memory");
            unsigned int old = atomicInc(counter, NFRAMES - 1);
            is_last = (old == NFRAMES - 2) ? 1 : 0;
        }
    }
    __syncthreads();

    // ---- last arriving block reduces all frames ----
    if (is_last) {
        const int s  = tid >> 3;    // scene 0..31
        const int l8 = tid & 7;     // 8 lanes per scene
        float fl = 0.f, fv = 0.f;
        #pragma unroll
        for (int j = 0; j < 4; ++j) {
            int fr = l8 + 8 * j;
            fl += __hip_atomic_load(&frame_loss[s * TT + fr],
                                    __ATOMIC_RELAXED, __HIP_MEMORY_SCOPE_AGENT);
            fv += __hip_atomic_load(&frame_valid[s * TT + fr],
                                    __ATOMIC_RELAXED, __HIP_MEMORY_SCOPE_AGENT);
        }
        #pragma unroll
        for (int m = 1; m < 8; m <<= 1) {
            fl += __shfl_xor(fl, m);
            fv += __shfl_xor(fv, m);
        }
        if (l8 == 0) sl[s] = fl / fmaxf(fv, 1.f);
        __syncthreads();
        if (tid < 64) {
            float v = (tid < BB) ? sl[tid] : 0.f;
            #pragma unroll
            for (int m = 1; m < 64; m <<= 1) v += __shfl_xor(v, m);
            if (tid == 0) out[0] = v / (float)BB;
        }
    }
}

extern "C" void kernel_launch(void* const* d_in, const int* in_sizes, int n_in,
                              void* d_out, int out_size, void* d_ws, size_t ws_size,
                              hipStream_t stream) {
    const float* x      = (const float*)d_in[0];
    const float* conf   = (const float*)d_in[1];
    const int*   ids    = (const int*)d_in[2];
    const float* scores = (const float*)d_in[3];
    const int*   tarr   = (const int*)d_in[4];
    const int*   mi     = (const int*)d_in[5];
    float* out = (float*)d_out;

    float* frame_loss  = (float*)d_ws;                    // [1024]
    float* frame_valid = frame_loss + NFRAMES;            // [1024]
    unsigned int* counter = (unsigned int*)(frame_valid + NFRAMES);

    fused_kernel<<<dim3(NFRAMES), 256, 0, stream>>>(
        x, conf, ids, scores, tarr, mi, frame_loss, frame_valid, counter, out);
}

// Round 7
// 23.755 us; speedup vs baseline: 1.4020x; 1.0238x over previous
//
#include <hip/hip_runtime.h>

#define BB 32
#define TT 32
#define GT_PER 8
#define PER 32
#define NN 1024
#define DD 256
#define NFRAMES (BB * TT)   // 1024

__device__ __forceinline__ float dot4(float4 a, float4 b) {
    return a.x * b.x + a.y * b.y + a.z * b.z + a.w * b.w;
}

// One block per (scene, frame). Hierarchical completion, all wave-local:
//   frame block -> per-scene ticket (32-way) -> scene winner wave reduces scene
//   -> global ticket (32-way) -> last scene winner writes out.
// Poison-tolerant tickets: atomicInc(ctr, K-1) wraps any start >= K-1 (incl.
// 0xAAAAAAAA poison and the steady-state K-1) to 0 on the first arriver; the
// K-th arriver sees old == K-2; counter self-restores to K-1 every call.
// Cross-XCD visibility: agent-scope relaxed atomics (IF$ coherence point) +
// s_waitcnt vmcnt(0) before each ticket RMW. No __threadfence (= buffer_wbl2).
__global__ __launch_bounds__(256, 4) void fused_kernel(
    const float* __restrict__ x, const float* __restrict__ conf,
    const int* __restrict__ ids, const float* __restrict__ scores,
    const int* __restrict__ tarr, const int* __restrict__ mi,
    float* __restrict__ frame_loss, float* __restrict__ frame_valid,
    float* __restrict__ scene_val, unsigned int* __restrict__ scounter,
    unsigned int* __restrict__ gcnt, float* __restrict__ out)
{
    __shared__ float sgt[GT_PER * DD];      // 8 KiB: gt rows [8][256] linear
    __shared__ float sdot[PER * 9];         // raw dots, stride 9 (conflict-free)
    __shared__ float snorm[PER];
    __shared__ int   sids[PER], smi[PER], st[PER];
    __shared__ float sconf[PER], sscore[PER];

    const int tid = threadIdx.x;
    const int b = blockIdx.x / TT;
    const int f = blockIdx.x % TT;
    const long n0 = (long)b * NN + (long)f * PER;
    const float4* xg4 = (const float4*)(x + n0 * DD);   // 32 rows x 64 float4

    const int G = tid >> 4;        // 0..15
    const int l = tid & 15;        // lane in group
    const int r0 = 2 * G, r1 = r0 + 1;

    // ---- each group loads its 2 rows into registers (sole global read of x) ----
    float4 a0[4], a1[4];
    #pragma unroll
    for (int j = 0; j < 4; ++j) {
        a0[j] = xg4[r0 * 64 + l + 16 * j];
        a1[j] = xg4[r1 * 64 + l + 16 * j];
    }
    // groups 0..3 own rows 0..7 (the GT rows): publish them to LDS from registers
    if (G < 4) {
        #pragma unroll
        for (int j = 0; j < 4; ++j) {
            *(float4*)&sgt[(r0 * 64 + l + 16 * j) * 4] = a0[j];
            *(float4*)&sgt[(r1 * 64 + l + 16 * j) * 4] = a1[j];
        }
    }
    if (tid < PER) {
        sids[tid]   = ids[n0 + tid];
        smi[tid]    = mi[n0 + tid];
        st[tid]     = tarr[n0 + tid];
        sconf[tid]  = conf[n0 + tid];
        sscore[tid] = scores[n0 + tid];
    }
    __syncthreads();

    // ---- dots of own 2 rows vs 8 gt rows + own norms ----
    {
        float nrm0 = 0.f, nrm1 = 0.f;
        #pragma unroll
        for (int j = 0; j < 4; ++j) {
            nrm0 += dot4(a0[j], a0[j]);
            nrm1 += dot4(a1[j], a1[j]);
        }
        float d0[GT_PER], d1[GT_PER];
        #pragma unroll
        for (int c = 0; c < GT_PER; ++c) {
            float s0 = 0.f, s1 = 0.f;
            #pragma unroll
            for (int j = 0; j < 4; ++j) {
                float4 bv = *(const float4*)&sgt[(c * 64 + l + 16 * j) * 4];
                s0 += dot4(a0[j], bv);
                s1 += dot4(a1[j], bv);
            }
            d0[c] = s0; d1[c] = s1;
        }
        // 16-lane butterfly reduce (masks 1,2,4,8 stay within the group)
        #pragma unroll
        for (int m = 1; m < 16; m <<= 1) {
            nrm0 += __shfl_xor(nrm0, m);
            nrm1 += __shfl_xor(nrm1, m);
            #pragma unroll
            for (int c = 0; c < GT_PER; ++c) {
                d0[c] += __shfl_xor(d0[c], m);
                d1[c] += __shfl_xor(d1[c], m);
            }
        }
        if (l == 0) {
            snorm[r0] = nrm0;
            snorm[r1] = nrm1;
            #pragma unroll
            for (int c = 0; c < GT_PER; ++c) {
                sdot[r0 * 9 + c] = d0[c];
                sdot[r1 * 9 + c] = d1[c];
            }
        }
    }
    __syncthreads();

    // ---- per-row CE + MSE, frame reduction, hierarchical epilogue (wave 0) ----
    if (tid < 64) {
        int r = tid;
        float contrib = 0.f;
        int packed = 0;   // valid | det<<8 | gt<<16
        if (r < PER) {
            bool validr = sids[r] >= 0;
            bool detr = validr && (smi[r] != 0);
            bool gtr  = validr && (smi[r] == 0);
            packed = (validr ? 1 : 0) | ((detr ? 1 : 0) << 8) | ((gtr ? 1 : 0) << 16);
            if (detr) {
                float sinr = rsqrtf(snorm[r]);
                float m = -1e30f;
                float tgt = 0.f;
                float simv[GT_PER];
                int cvmask = 0;
                #pragma unroll
                for (int c = 0; c < GT_PER; ++c) {
                    bool cv = (sids[c] >= 0) && (smi[c] == 0) && (st[c] == st[r]);
                    float s = 10.f * sdot[r * 9 + c] * sinr * rsqrtf(snorm[c]);
                    simv[c] = s;
                    if (cv) {
                        cvmask |= (1 << c);
                        m = fmaxf(m, s);
                        if (sids[c] == sids[r]) tgt += s;
                    }
                }
                float se = 0.f;
                #pragma unroll
                for (int c = 0; c < GT_PER; ++c) {
                    if (cvmask & (1 << c)) se += expf(simv[c] - m);
                }
                float lse = m + logf(se);
                float ce = lse - tgt;
                float df = sconf[r] - sscore[r];
                contrib = ce + df * df;
            }
        }
        #pragma unroll
        for (int mask = 1; mask < 64; mask <<= 1) {
            contrib += __shfl_xor(contrib, mask);
            packed  += __shfl_xor(packed, mask);
        }

        // publish frame partial + per-scene ticket
        unsigned int old = 0;
        if (tid == 0) {
            int vcnt = packed & 0xff;
            int dcnt = (packed >> 8) & 0xff;
            int gcnt_ = (packed >> 16) & 0xff;
            bool vf = (vcnt > 0) && (dcnt > 0) && (gcnt_ > 0);
            float denom = fmaxf((float)dcnt, 1.f);
            __hip_atomic_store(&frame_loss[blockIdx.x], vf ? (contrib / denom) : 0.f,
                               __ATOMIC_RELAXED, __HIP_MEMORY_SCOPE_AGENT);
            __hip_atomic_store(&frame_valid[blockIdx.x], vf ? 1.f : 0.f,
                               __ATOMIC_RELAXED, __HIP_MEMORY_SCOPE_AGENT);
            asm volatile("s_waitcnt vmcnt(0)" ::: "memory");
            old = atomicInc(&scounter[b], TT - 1);
        }
        old = __shfl(old, 0);

        if (old == TT - 2) {            // this wave won scene b
            float fl = 0.f, fv = 0.f;
            if (tid < TT) {
                fl = __hip_atomic_load(&frame_loss[b * TT + tid],
                                       __ATOMIC_RELAXED, __HIP_MEMORY_SCOPE_AGENT);
                fv = __hip_atomic_load(&frame_valid[b * TT + tid],
                                       __ATOMIC_RELAXED, __HIP_MEMORY_SCOPE_AGENT);
            }
            #pragma unroll
            for (int m = 1; m < 32; m <<= 1) {
                fl += __shfl_xor(fl, m);
                fv += __shfl_xor(fv, m);
            }
            unsigned int old2 = 0;
            if (tid == 0) {
                __hip_atomic_store(&scene_val[b], fl / fmaxf(fv, 1.f),
                                   __ATOMIC_RELAXED, __HIP_MEMORY_SCOPE_AGENT);
                asm volatile("s_waitcnt vmcnt(0)" ::: "memory");
                old2 = atomicInc(gcnt, BB - 1);
            }
            old2 = __shfl(old2, 0);

            if (old2 == BB - 2) {       // last scene done: write the mean
                float v = 0.f;
                if (tid < BB) {
                    v = __hip_atomic_load(&scene_val[tid],
                                          __ATOMIC_RELAXED, __HIP_MEMORY_SCOPE_AGENT);
                }
                #pragma unroll
                for (int m = 1; m < 32; m <<= 1) v += __shfl_xor(v, m);
                if (tid == 0) out[0] = v / (float)BB;
            }
        }
    }
}

extern "C" void kernel_launch(void* const* d_in, const int* in_sizes, int n_in,
                              void* d_out, int out_size, void* d_ws, size_t ws_size,
                              hipStream_t stream) {
    const float* x      = (const float*)d_in[0];
    const float* conf   = (const float*)d_in[1];
    const int*   ids    = (const int*)d_in[2];
    const float* scores = (const float*)d_in[3];
    const int*   tarr   = (const int*)d_in[4];
    const int*   mi     = (const int*)d_in[5];
    float* out = (float*)d_out;

    float* frame_loss  = (float*)d_ws;                       // [1024]
    float* frame_valid = frame_loss + NFRAMES;               // [1024]
    float* scene_val   = frame_valid + NFRAMES;              // [32]
    unsigned int* scounter = (unsigned int*)(scene_val + BB);// [32]
    unsigned int* gcnt     = scounter + BB;                  // [1]

    fused_kernel<<<dim3(NFRAMES), 256, 0, stream>>>(
        x, conf, ids, scores, tarr, mi, frame_loss, frame_valid,
        scene_val, scounter, gcnt, out);
}

// Round 8
// 16.671 us; speedup vs baseline: 1.9977x; 1.4249x over previous
//
#include <hip/hip_runtime.h>

#define BB 32
#define TT 32
#define GT_PER 8
#define PER 32
#define NN 1024
#define DD 256
#define NFRAMES (BB * TT)   // 1024

__device__ __forceinline__ float dot4(float4 a, float4 b) {
    return a.x * b.x + a.y * b.y + a.z * b.z + a.w * b.w;
}

// One block per (scene, frame). 16 groups x 16 lanes; group g owns rows 2g,2g+1
// in registers. GT rows (0..7) staged to LDS by groups 0..3. The 16-lane
// xor-butterfly is an ALL-reduce, so after it every lane holds the full dots
// for both rows -> no sdot LDS round-trip; lanes 0/1 of each group compute
// their row's CE directly (32-way parallel epilogue).
__global__ __launch_bounds__(256) void frame_kernel(
    const float* __restrict__ x, const float* __restrict__ conf,
    const int* __restrict__ ids, const float* __restrict__ scores,
    const int* __restrict__ tarr, const int* __restrict__ mi,
    float* __restrict__ frame_loss, float* __restrict__ frame_valid)
{
    __shared__ float sgt[GT_PER * DD];      // 8 KiB: gt rows [8][256] linear
    __shared__ float snorm[PER];
    __shared__ int   sids[PER], smi[PER], st[PER];
    __shared__ float sconf[PER], sscore[PER];
    __shared__ float pc[4];                 // per-wave contrib partials
    __shared__ int   pp[4];                 // per-wave packed partials

    const int tid = threadIdx.x;
    const int b = blockIdx.x / TT;
    const int f = blockIdx.x % TT;
    const long n0 = (long)b * NN + (long)f * PER;
    const float4* xg4 = (const float4*)(x + n0 * DD);   // 32 rows x 64 float4

    const int G = tid >> 4;        // 0..15
    const int l = tid & 15;        // lane in group
    const int r0 = 2 * G, r1 = r0 + 1;

    // ---- each group loads its 2 rows into registers (sole global read of x) ----
    float4 a0[4], a1[4];
    #pragma unroll
    for (int j = 0; j < 4; ++j) {
        a0[j] = xg4[r0 * 64 + l + 16 * j];
        a1[j] = xg4[r1 * 64 + l + 16 * j];
    }
    if (tid < PER) {
        sids[tid]   = ids[n0 + tid];
        smi[tid]    = mi[n0 + tid];
        st[tid]     = tarr[n0 + tid];
        sconf[tid]  = conf[n0 + tid];
        sscore[tid] = scores[n0 + tid];
    }
    // norms: register-only, publish before the sync
    float nrm0 = 0.f, nrm1 = 0.f;
    #pragma unroll
    for (int j = 0; j < 4; ++j) {
        nrm0 += dot4(a0[j], a0[j]);
        nrm1 += dot4(a1[j], a1[j]);
    }
    #pragma unroll
    for (int m = 1; m < 16; m <<= 1) {
        nrm0 += __shfl_xor(nrm0, m);
        nrm1 += __shfl_xor(nrm1, m);
    }
    if (l == 0) { snorm[r0] = nrm0; snorm[r1] = nrm1; }
    // groups 0..3 own rows 0..7 (the GT rows): publish them to LDS from registers
    if (G < 4) {
        #pragma unroll
        for (int j = 0; j < 4; ++j) {
            *(float4*)&sgt[(r0 * 64 + l + 16 * j) * 4] = a0[j];
            *(float4*)&sgt[(r1 * 64 + l + 16 * j) * 4] = a1[j];
        }
    }
    __syncthreads();

    // ---- dots of own 2 rows vs 8 gt rows; butterfly = all-reduce ----
    float d0[GT_PER], d1[GT_PER];
    #pragma unroll
    for (int c = 0; c < GT_PER; ++c) {
        float s0 = 0.f, s1 = 0.f;
        #pragma unroll
        for (int j = 0; j < 4; ++j) {
            float4 bv = *(const float4*)&sgt[(c * 64 + l + 16 * j) * 4];
            s0 += dot4(a0[j], bv);
            s1 += dot4(a1[j], bv);
        }
        d0[c] = s0; d1[c] = s1;
    }
    #pragma unroll
    for (int m = 1; m < 16; m <<= 1) {
        #pragma unroll
        for (int c = 0; c < GT_PER; ++c) {
            d0[c] += __shfl_xor(d0[c], m);
            d1[c] += __shfl_xor(d1[c], m);
        }
    }

    // ---- distributed epilogue: lane 0 handles r0, lane 1 handles r1 ----
    float contrib = 0.f;
    int packed = 0;   // valid | det<<8 | gt<<16
    if (l < 2) {
        const int r = r0 + l;
        float dv[GT_PER];
        #pragma unroll
        for (int c = 0; c < GT_PER; ++c) dv[c] = l ? d1[c] : d0[c];
        const float nrmr = l ? nrm1 : nrm0;

        bool validr = sids[r] >= 0;
        bool detr = validr && (smi[r] != 0);
        bool gtr  = validr && (smi[r] == 0);
        packed = (validr ? 1 : 0) | ((detr ? 1 : 0) << 8) | ((gtr ? 1 : 0) << 16);
        if (detr) {
            float sinr = rsqrtf(nrmr);
            float m = -1e30f;
            float tgt = 0.f;
            float simv[GT_PER];
            int cvmask = 0;
            #pragma unroll
            for (int c = 0; c < GT_PER; ++c) {
                bool cv = (sids[c] >= 0) && (smi[c] == 0) && (st[c] == st[r]);
                float s = 10.f * dv[c] * sinr * rsqrtf(snorm[c]);
                simv[c] = s;
                if (cv) {
                    cvmask |= (1 << c);
                    m = fmaxf(m, s);
                    if (sids[c] == sids[r]) tgt += s;
                }
            }
            float se = 0.f;
            #pragma unroll
            for (int c = 0; c < GT_PER; ++c) {
                if (cvmask & (1 << c)) se += expf(simv[c] - m);
            }
            float lse = m + logf(se);
            float ce = lse - tgt;
            float df = sconf[r] - sscore[r];
            contrib = ce + df * df;
        }
    }

    // ---- block reduction: full-wave butterfly, then 4 wave partials in LDS ----
    #pragma unroll
    for (int m = 1; m < 64; m <<= 1) {
        contrib += __shfl_xor(contrib, m);
        packed  += __shfl_xor(packed, m);
    }
    const int wid = tid >> 6;
    if ((tid & 63) == 0) { pc[wid] = contrib; pp[wid] = packed; }
    __syncthreads();
    if (tid == 0) {
        float csum = pc[0] + pc[1] + pc[2] + pc[3];
        int   psum = pp[0] + pp[1] + pp[2] + pp[3];
        int vcnt = psum & 0xff;
        int dcnt = (psum >> 8) & 0xff;
        int gcnt = (psum >> 16) & 0xff;
        bool vf = (vcnt > 0) && (dcnt > 0) && (gcnt > 0);
        float denom = fmaxf((float)dcnt, 1.f);
        frame_loss[blockIdx.x]  = vf ? (csum / denom) : 0.f;
        frame_valid[blockIdx.x] = vf ? 1.f : 0.f;
    }
}

// One 256-thread block: thread t sums 4 frames; 8 threads per scene.
__global__ __launch_bounds__(256) void finalize_kernel(
    const float* __restrict__ frame_loss, const float* __restrict__ frame_valid,
    float* __restrict__ out)
{
    __shared__ float sl[BB];
    const int tid = threadIdx.x;           // 0..255
    float fl = 0.f, fv = 0.f;
    #pragma unroll
    for (int j = 0; j < 4; ++j) {
        fl += frame_loss[tid * 4 + j];
        fv += frame_valid[tid * 4 + j];
    }
    // reduce over the 8 threads of one scene (masks 1,2,4 stay in-wave)
    #pragma unroll
    for (int m = 1; m < 8; m <<= 1) {
        fl += __shfl_xor(fl, m);
        fv += __shfl_xor(fv, m);
    }
    if ((tid & 7) == 0) sl[tid >> 3] = fl / fmaxf(fv, 1.f);
    __syncthreads();
    if (tid < 32) {
        float v = sl[tid];
        #pragma unroll
        for (int m = 1; m < 32; m <<= 1) v += __shfl_xor(v, m);
        if (tid == 0) out[0] = v / (float)BB;
    }
}

extern "C" void kernel_launch(void* const* d_in, const int* in_sizes, int n_in,
                              void* d_out, int out_size, void* d_ws, size_t ws_size,
                              hipStream_t stream) {
    const float* x      = (const float*)d_in[0];
    const float* conf   = (const float*)d_in[1];
    const int*   ids    = (const int*)d_in[2];
    const float* scores = (const float*)d_in[3];
    const int*   tarr   = (const int*)d_in[4];
    const int*   mi     = (const int*)d_in[5];
    float* out = (float*)d_out;

    float* frame_loss  = (float*)d_ws;            // [1024]
    float* frame_valid = frame_loss + NFRAMES;    // [1024]

    frame_kernel<<<dim3(NFRAMES), 256, 0, stream>>>(
        x, conf, ids, scores, tarr, mi, frame_loss, frame_valid);
    finalize_kernel<<<1, 256, 0, stream>>>(frame_loss, frame_valid, out);
}

// Round 10
// 16.322 us; speedup vs baseline: 2.0405x; 1.0214x over previous
//
#include <hip/hip_runtime.h>

#define BB 32
#define TT 32
#define GT_PER 8
#define PER 32
#define NN 1024
#define DD 256
#define NFRAMES (BB * TT)   // 1024

typedef float vfloat4 __attribute__((ext_vector_type(4)));

__device__ __forceinline__ float dot4(vfloat4 a, vfloat4 b) {
    return a.x * b.x + a.y * b.y + a.z * b.z + a.w * b.w;
}

// One block per (scene, frame). 16 groups x 16 lanes; group g owns rows 2g,2g+1
// in registers (nontemporal loads: x is read exactly once, don't allocate in
// L1/L2). GT rows (0..7) staged to LDS by groups 0..3. The 16-lane
// xor-butterfly is an ALL-reduce, so every lane ends with the full dot set;
// lanes 0/1 of each group compute their row's CE (32-way parallel epilogue).
__global__ __launch_bounds__(256) void frame_kernel(
    const float* __restrict__ x, const float* __restrict__ conf,
    const int* __restrict__ ids, const float* __restrict__ scores,
    const int* __restrict__ tarr, const int* __restrict__ mi,
    float* __restrict__ frame_loss, float* __restrict__ frame_valid)
{
    __shared__ float sgt[GT_PER * DD];      // 8 KiB: gt rows [8][256] linear
    __shared__ float snorm[PER];
    __shared__ int   sids[PER], smi[PER], st[PER];
    __shared__ float sconf[PER], sscore[PER];
    __shared__ float pc[4];                 // per-wave contrib partials
    __shared__ int   pp[4];                 // per-wave packed partials

    const int tid = threadIdx.x;
    const int b = blockIdx.x / TT;
    const int f = blockIdx.x % TT;
    const long n0 = (long)b * NN + (long)f * PER;
    const vfloat4* xg4 = (const vfloat4*)(x + n0 * DD);   // 32 rows x 64 vec4

    const int G = tid >> 4;        // 0..15
    const int l = tid & 15;        // lane in group
    const int r0 = 2 * G, r1 = r0 + 1;

    // metadata first (tiny, 5 cache lines) so it's in flight before the bulk
    int   mid = 0, mmi = 0, mt = 0;
    float mconf = 0.f, mscore = 0.f;
    if (tid < PER) {
        mid    = ids[n0 + tid];
        mmi    = mi[n0 + tid];
        mt     = tarr[n0 + tid];
        mconf  = conf[n0 + tid];
        mscore = scores[n0 + tid];
    }

    // ---- each group streams its 2 rows into registers (read-once: nt loads) ----
    vfloat4 a0[4], a1[4];
    #pragma unroll
    for (int j = 0; j < 4; ++j) {
        a0[j] = __builtin_nontemporal_load(&xg4[r0 * 64 + l + 16 * j]);
        a1[j] = __builtin_nontemporal_load(&xg4[r1 * 64 + l + 16 * j]);
    }
    if (tid < PER) {
        sids[tid]   = mid;
        smi[tid]    = mmi;
        st[tid]     = mt;
        sconf[tid]  = mconf;
        sscore[tid] = mscore;
    }
    // norms: register-only, publish before the sync
    float nrm0 = 0.f, nrm1 = 0.f;
    #pragma unroll
    for (int j = 0; j < 4; ++j) {
        nrm0 += dot4(a0[j], a0[j]);
        nrm1 += dot4(a1[j], a1[j]);
    }
    #pragma unroll
    for (int m = 1; m < 16; m <<= 1) {
        nrm0 += __shfl_xor(nrm0, m);
        nrm1 += __shfl_xor(nrm1, m);
    }
    if (l == 0) { snorm[r0] = nrm0; snorm[r1] = nrm1; }
    // groups 0..3 own rows 0..7 (the GT rows): publish them to LDS from registers
    if (G < 4) {
        #pragma unroll
        for (int j = 0; j < 4; ++j) {
            *(vfloat4*)&sgt[(r0 * 64 + l + 16 * j) * 4] = a0[j];
            *(vfloat4*)&sgt[(r1 * 64 + l + 16 * j) * 4] = a1[j];
        }
    }
    __syncthreads();

    // ---- dots of own 2 rows vs 8 gt rows; butterfly = all-reduce ----
    float d0[GT_PER], d1[GT_PER];
    #pragma unroll
    for (int c = 0; c < GT_PER; ++c) {
        float s0 = 0.f, s1 = 0.f;
        #pragma unroll
        for (int j = 0; j < 4; ++j) {
            vfloat4 bv = *(const vfloat4*)&sgt[(c * 64 + l + 16 * j) * 4];
            s0 += dot4(a0[j], bv);
            s1 += dot4(a1[j], bv);
        }
        d0[c] = s0; d1[c] = s1;
    }
    #pragma unroll
    for (int m = 1; m < 16; m <<= 1) {
        #pragma unroll
        for (int c = 0; c < GT_PER; ++c) {
            d0[c] += __shfl_xor(d0[c], m);
            d1[c] += __shfl_xor(d1[c], m);
        }
    }

    // ---- distributed epilogue: lane 0 handles r0, lane 1 handles r1 ----
    float contrib = 0.f;
    int packed = 0;   // valid | det<<8 | gt<<16
    if (l < 2) {
        const int r = r0 + l;
        float dv[GT_PER];
        #pragma unroll
        for (int c = 0; c < GT_PER; ++c) dv[c] = l ? d1[c] : d0[c];
        const float nrmr = l ? nrm1 : nrm0;

        bool validr = sids[r] >= 0;
        bool detr = validr && (smi[r] != 0);
        bool gtr  = validr && (smi[r] == 0);
        packed = (validr ? 1 : 0) | ((detr ? 1 : 0) << 8) | ((gtr ? 1 : 0) << 16);
        if (detr) {
            float sinr = rsqrtf(nrmr);
            float m = -1e30f;
            float tgt = 0.f;
            float simv[GT_PER];
            int cvmask = 0;
            #pragma unroll
            for (int c = 0; c < GT_PER; ++c) {
                bool cv = (sids[c] >= 0) && (smi[c] == 0) && (st[c] == st[r]);
                float s = 10.f * dv[c] * sinr * rsqrtf(snorm[c]);
                simv[c] = s;
                if (cv) {
                    cvmask |= (1 << c);
                    m = fmaxf(m, s);
                    if (sids[c] == sids[r]) tgt += s;
                }
            }
            float se = 0.f;
            #pragma unroll
            for (int c = 0; c < GT_PER; ++c) {
                if (cvmask & (1 << c)) se += expf(simv[c] - m);
            }
            float lse = m + logf(se);
            float ce = lse - tgt;
            float df = sconf[r] - sscore[r];
            contrib = ce + df * df;
        }
    }

    // ---- block reduction: full-wave butterfly, then 4 wave partials in LDS ----
    #pragma unroll
    for (int m = 1; m < 64; m <<= 1) {
        contrib += __shfl_xor(contrib, m);
        packed  += __shfl_xor(packed, m);
    }
    const int wid = tid >> 6;
    if ((tid & 63) == 0) { pc[wid] = contrib; pp[wid] = packed; }
    __syncthreads();
    if (tid == 0) {
        float csum = pc[0] + pc[1] + pc[2] + pc[3];
        int   psum = pp[0] + pp[1] + pp[2] + pp[3];
        int vcnt = psum & 0xff;
        int dcnt = (psum >> 8) & 0xff;
        int gcnt = (psum >> 16) & 0xff;
        bool vf = (vcnt > 0) && (dcnt > 0) && (gcnt > 0);
        float denom = fmaxf((float)dcnt, 1.f);
        frame_loss[blockIdx.x]  = vf ? (csum / denom) : 0.f;
        frame_valid[blockIdx.x] = vf ? 1.f : 0.f;
    }
}

// One 256-thread block: thread t sums 4 frames; 8 threads per scene.
__global__ __launch_bounds__(256) void finalize_kernel(
    const float* __restrict__ frame_loss, const float* __restrict__ frame_valid,
    float* __restrict__ out)
{
    __shared__ float sl[BB];
    const int tid = threadIdx.x;           // 0..255
    float fl = 0.f, fv = 0.f;
    #pragma unroll
    for (int j = 0; j < 4; ++j) {
        fl += frame_loss[tid * 4 + j];
        fv += frame_valid[tid * 4 + j];
    }
    // reduce over the 8 threads of one scene (masks 1,2,4 stay in-wave)
    #pragma unroll
    for (int m = 1; m < 8; m <<= 1) {
        fl += __shfl_xor(fl, m);
        fv += __shfl_xor(fv, m);
    }
    if ((tid & 7) == 0) sl[tid >> 3] = fl / fmaxf(fv, 1.f);
    __syncthreads();
    if (tid < 32) {
        float v = sl[tid];
        #pragma unroll
        for (int m = 1; m < 32; m <<= 1) v += __shfl_xor(v, m);
        if (tid == 0) out[0] = v / (float)BB;
    }
}

extern "C" void kernel_launch(void* const* d_in, const int* in_sizes, int n_in,
                              void* d_out, int out_size, void* d_ws, size_t ws_size,
                              hipStream_t stream) {
    const float* x      = (const float*)d_in[0];
    const float* conf   = (const float*)d_in[1];
    const int*   ids    = (const int*)d_in[2];
    const float* scores = (const float*)d_in[3];
    const int*   tarr   = (const int*)d_in[4];
    const int*   mi     = (const int*)d_in[5];
    float* out = (float*)d_out;

    float* frame_loss  = (float*)d_ws;            // [1024]
    float* frame_valid = frame_loss + NFRAMES;    // [1024]

    frame_kernel<<<dim3(NFRAMES), 256, 0, stream>>>(
        x, conf, ids, scores, tarr, mi, frame_loss, frame_valid);
    finalize_kernel<<<1, 256, 0, stream>>>(frame_loss, frame_valid, out);
}